// Round 1
// baseline (15140.601 us; speedup 1.0000x reference)
//
#include <hip/hip_runtime.h>
#include <stdint.h>

// Problem constants
#define LNUM 4
#define BB   32
#define TT   2048
#define DD   512
#define HH   512
#define BT   (BB*TT)          // 65536
#define EPSF 1e-5f

typedef __attribute__((ext_vector_type(8))) _Float16 h8;   // 4 VGPR MFMA A/B frag
typedef __attribute__((ext_vector_type(4))) float    f4;   // MFMA C/D frag

// ---------------- workspace layout (bytes) ----------------
#define WS_X16    ((size_t)0)                         // x as f16, 64 MiB
#define WS_WBLOB  (WS_X16 + (size_t)BT*DD*2)          // 9 weight mats in frag-blob order, 4.5 MiB
#define WS_LNI    (WS_WBLOB + (size_t)9*16*32*64*8*2) // LN(zi) f16 [l][t][b][h], 256 MiB
#define WS_H3     (WS_LNI + (size_t)LNUM*TT*BB*HH*2)  // h[3] f16 [b][t][h], 64 MiB
#define WS_HEX    (WS_H3  + (size_t)BB*TT*HH*2)       // 16 blocks x 8KB h-half exchange
#define WS_SEX    (WS_HEX + (size_t)16*8192)          // 16 x 16 x 2 f32 LN-stats exchange
#define WS_FLAGS  (WS_SEX + (size_t)2048)             // [0..15]=S flags, [16..31]=H flags
#define WS_END    (WS_FLAGS + (size_t)256)

// ---------------- prep: x f32 -> f16 ----------------
__global__ void k_prep_x(const float* __restrict__ x, _Float16* __restrict__ x16) {
  size_t i = ((size_t)blockIdx.x*256 + threadIdx.x) * 8;
  float4 a = *(const float4*)(x + i);
  float4 b = *(const float4*)(x + i + 4);
  h8 h;
  h[0]=(_Float16)a.x; h[1]=(_Float16)a.y; h[2]=(_Float16)a.z; h[3]=(_Float16)a.w;
  h[4]=(_Float16)b.x; h[5]=(_Float16)b.y; h[6]=(_Float16)b.z; h[7]=(_Float16)b.w;
  *(h8*)(x16 + i) = h;
}

// ---------------- prep: weights -> f16 fragment blobs ----------------
// blob elem index: (((wi*16+kt)*32 + nt)*64 + lane)*8 + e  == W[n][k],
//   n = nt*16 + (lane&15), k = kt*32 + (lane>>4)*8 + e   (MFMA B-frag layout)
__global__ void k_prep_w(const float* __restrict__ Wih, const float* __restrict__ Whh,
                         const float* __restrict__ Who, _Float16* __restrict__ wblob) {
  int wi = blockIdx.x >> 4;
  int kt = blockIdx.x & 15;
  const float* S = (wi < 4) ? (Wih + (size_t)wi*HH*DD)
                 : (wi < 8) ? (Whh + (size_t)(wi-4)*HH*HH)
                            :  Who;
  for (int it = 0; it < 8; ++it) {
    int flat = it*256 + threadIdx.x;          // 0..2047 = nt*64+lane
    int lane = flat & 63;
    int n  = (flat >> 6)*16 + (lane & 15);
    int k0 = kt*32 + (lane >> 4)*8;
    const float* s = S + (size_t)n*512 + k0;
    h8 h;
    #pragma unroll
    for (int e = 0; e < 8; ++e) h[e] = (_Float16)s[e];
    *(h8*)(wblob + (size_t)(wi*16+kt)*16384 + (size_t)flat*8) = h;
  }
}

// ---------------- phase A: zi GEMM + fused LayerNorm -> LNi f16 ----------------
// C[r][j] = sum_k x[r][k]*W_ih[l][j][k] + b_ih ; LN over j ; store LNi[l][t][b][j]
__launch_bounds__(256,1)
__global__ void k_gemm_lni(const _Float16* __restrict__ x16,
                           const _Float16* __restrict__ wblob,
                           const float* __restrict__ b_ih,
                           const float* __restrict__ g_ih,
                           const float* __restrict__ be_ih,
                           _Float16* __restrict__ lni) {
  __shared__ __align__(16) _Float16 Bst[16384];   // 32 KB frag-order W chunk
  __shared__ __align__(16) char     Ast[64*80];   // 64 rows x 32 f16, 80B padded stride
  __shared__ float stats[4][4][16][2];
  int tid = threadIdx.x, lane = tid & 63, w = tid >> 6;
  int l   = blockIdx.x >> 10;
  int rb0 = (blockIdx.x & 1023) * 64;

  float breg[8], greg[8], bereg[8];
  #pragma unroll
  for (int i = 0; i < 8; ++i) {
    int j = (w*8+i)*16 + (lane & 15);
    breg[i]  = b_ih [l*512 + j];
    greg[i]  = g_ih [l*512 + j];
    bereg[i] = be_ih[l*512 + j];
  }
  f4 acc[4][8];
  #pragma unroll
  for (int mt = 0; mt < 4; ++mt)
    #pragma unroll
    for (int i = 0; i < 8; ++i) acc[mt][i] = (f4){0.f,0.f,0.f,0.f};

  for (int kt = 0; kt < 16; ++kt) {
    const _Float16* bsrc = wblob + (size_t)(l*16 + kt)*16384;
    #pragma unroll
    for (int it = 0; it < 8; ++it) {
      int off = it*2048 + tid*8;
      *(uint4*)&Bst[off] = *(const uint4*)&bsrc[off];
    }
    { int row = tid >> 2, slot = tid & 3;
      const _Float16* asrc = x16 + (size_t)(rb0+row)*512 + kt*32 + slot*8;
      *(uint4*)&Ast[row*80 + slot*16] = *(const uint4*)asrc; }
    __syncthreads();
    h8 af[4];
    #pragma unroll
    for (int mt = 0; mt < 4; ++mt)
      af[mt] = *(const h8*)&Ast[(mt*16 + (lane&15))*80 + (lane>>4)*16];
    #pragma unroll
    for (int i = 0; i < 8; ++i) {
      h8 bf = *(const h8*)&Bst[((w*8+i)*64 + lane)*8];
      #pragma unroll
      for (int mt = 0; mt < 4; ++mt)
        acc[mt][i] = __builtin_amdgcn_mfma_f32_16x16x32_f16(af[mt], bf, acc[mt][i], 0,0,0);
    }
    __syncthreads();
  }
  // epilogue: bias + LN stats (row = rb0 + mt*16 + (lane>>4)*4 + r, col j)
  float ps[4][4], pq[4][4];
  #pragma unroll
  for (int mt = 0; mt < 4; ++mt)
    #pragma unroll
    for (int r = 0; r < 4; ++r) { ps[mt][r] = 0.f; pq[mt][r] = 0.f; }
  #pragma unroll
  for (int mt = 0; mt < 4; ++mt)
    #pragma unroll
    for (int i = 0; i < 8; ++i)
      #pragma unroll
      for (int r = 0; r < 4; ++r) {
        float v = acc[mt][i][r] + breg[i];
        acc[mt][i][r] = v;
        ps[mt][r] += v; pq[mt][r] += v*v;
      }
  #pragma unroll
  for (int m = 1; m < 16; m <<= 1)
    #pragma unroll
    for (int mt = 0; mt < 4; ++mt)
      #pragma unroll
      for (int r = 0; r < 4; ++r) {
        ps[mt][r] += __shfl_xor(ps[mt][r], m);
        pq[mt][r] += __shfl_xor(pq[mt][r], m);
      }
  if ((lane & 15) == 0) {
    int g = lane >> 4;
    #pragma unroll
    for (int mt = 0; mt < 4; ++mt)
      #pragma unroll
      for (int r = 0; r < 4; ++r) {
        stats[w][mt][g*4+r][0] = ps[mt][r];
        stats[w][mt][g*4+r][1] = pq[mt][r];
      }
  }
  __syncthreads();
  #pragma unroll
  for (int mt = 0; mt < 4; ++mt)
    #pragma unroll
    for (int r = 0; r < 4; ++r) {
      int rowm = (lane>>4)*4 + r;
      float s = 0.f, q = 0.f;
      #pragma unroll
      for (int ww = 0; ww < 4; ++ww) { s += stats[ww][mt][rowm][0]; q += stats[ww][mt][rowm][1]; }
      float mu = s * (1.f/512.f);
      float rs = rsqrtf(q*(1.f/512.f) - mu*mu + EPSF);
      int rglob = rb0 + mt*16 + rowm;
      int b = rglob >> 11, t = rglob & 2047;
      _Float16* dst = lni + ((size_t)(l*2048 + t)*32 + b)*512;
      #pragma unroll
      for (int i = 0; i < 8; ++i) {
        int j = (w*8+i)*16 + (lane & 15);
        dst[j] = (_Float16)((acc[mt][i][r] - mu)*rs*greg[i] + bereg[i]);
      }
    }
}

// ---------------- recurrence: 16 blocks, W_hh half in registers ----------------
// block: l=(bid&7)>>1, ch=bid&1 (16 chains b=ch*16+c), jh=bid>>3 (j-half); partner=bid^8
__launch_bounds__(256,1)
__global__ void k_rnn(const _Float16* __restrict__ wblob,
                      const _Float16* __restrict__ lni,
                      const float* __restrict__ b_hh,
                      const float* __restrict__ g_hh,
                      const float* __restrict__ be_hh,
                      _Float16* __restrict__ h3,
                      float* __restrict__ hfin,
                      _Float16* __restrict__ hex,
                      float* __restrict__ sex,
                      unsigned int* __restrict__ flags) {
  __shared__ __align__(16) _Float16 hblob[16*64*8];      // h in A-frag blob layout, 16 KB
  __shared__ __align__(16) _Float16 lniS[2][16*264];     // staged LNi rows (padded), 2 bufs
  __shared__ float stats[4][16][2];
  __shared__ float bstats[16][2];

  int tid = threadIdx.x, lane = tid & 63, w = tid >> 6;
  int bid = blockIdx.x;
  int l = (bid & 7) >> 1, ch = bid & 1, jh = bid >> 3;
  int pbid = bid ^ 8;
  unsigned int* Sflag = flags;
  unsigned int* Hflag = flags + 16;
  const int ownkt0 = jh*8, othkt0 = (jh^1)*8;

  // W_hh half -> registers (own kt-half first for static indexing)
  h8 wf[16][4];
  #pragma unroll
  for (int q = 0; q < 16; ++q) {
    int kt = (q < 8) ? (jh*8 + q) : ((jh^1)*8 + (q-8));
    #pragma unroll
    for (int i = 0; i < 4; ++i) {
      int nt = jh*16 + w*4 + i;
      wf[q][i] = *(const h8*)(wblob + (size_t)(((4+l)*16 + kt)*32 + nt)*512 + lane*8);
    }
  }
  float bh[4], gh[4], beh[4];
  #pragma unroll
  for (int i = 0; i < 4; ++i) {
    int j = (jh*16 + w*4 + i)*16 + (lane & 15);
    bh[i] = b_hh[l*512 + j]; gh[i] = g_hh[l*512 + j]; beh[i] = be_hh[l*512 + j];
  }
  // h0 = 0
  { uint4 z4 = make_uint4(0,0,0,0);
    for (int o = tid*8; o < 16*64*8; o += 256*8) *(uint4*)&hblob[o] = z4; }
  // stage LNi[t=0]
  { int c = tid >> 4, seg = tid & 15;
    const _Float16* src = lni + ((size_t)(l*2048 + 0)*32 + ch*16 + c)*512 + jh*256 + seg*16;
    *(uint4*)&lniS[0][c*264 + seg*16]     = *(const uint4*)src;
    *(uint4*)&lniS[0][c*264 + seg*16 + 8] = *(const uint4*)(src + 8); }
  __syncthreads();

  #pragma unroll 1
  for (int t = 0; t < TT; ++t) {
    // prefetch LNi[t+1] to regs
    uint4 p0 = make_uint4(0,0,0,0), p1 = p0;
    bool pf = (t+1 < TT);
    if (pf) {
      int c = tid >> 4, seg = tid & 15;
      const _Float16* src = lni + ((size_t)(l*2048 + (t+1))*32 + ch*16 + c)*512 + jh*256 + seg*16;
      p0 = *(const uint4*)src; p1 = *(const uint4*)(src + 8);
    }
    f4 acc[4];
    #pragma unroll
    for (int i = 0; i < 4; ++i) acc[i] = (f4){0.f,0.f,0.f,0.f};
    // M1: own kt-half (own h-half is local)
    #pragma unroll
    for (int q = 0; q < 8; ++q) {
      h8 a = *(const h8*)&hblob[((ownkt0 + q)*64 + lane)*8];
      #pragma unroll
      for (int i = 0; i < 4; ++i)
        acc[i] = __builtin_amdgcn_mfma_f32_16x16x32_f16(a, wf[q][i], acc[i], 0,0,0);
    }
    // X: pull partner h-half
    if (t > 0) {
      if (tid == 0) {
        int guard = 0;
        while (__hip_atomic_load(&Hflag[pbid], __ATOMIC_ACQUIRE, __HIP_MEMORY_SCOPE_AGENT)
               < (unsigned)t) { __builtin_amdgcn_s_sleep(1); if (++guard > (1<<26)) break; }
      }
      __syncthreads();
      { const unsigned int* src =
          (const unsigned int*)((const char*)hex + (size_t)pbid*8192) + tid*8;
        unsigned int v[8];
        #pragma unroll
        for (int k = 0; k < 8; ++k)
          v[k] = __hip_atomic_load(src + k, __ATOMIC_RELAXED, __HIP_MEMORY_SCOPE_AGENT);
        char* dst = (char*)&hblob[othkt0*64*8] + tid*32;
        *(uint4*)dst      = make_uint4(v[0],v[1],v[2],v[3]);
        *(uint4*)(dst+16) = make_uint4(v[4],v[5],v[6],v[7]); }
      __syncthreads();
    }
    // M2: partner kt-half
    #pragma unroll
    for (int q = 8; q < 16; ++q) {
      h8 a = *(const h8*)&hblob[((othkt0 + (q-8))*64 + lane)*8];
      #pragma unroll
      for (int i = 0; i < 4; ++i)
        acc[i] = __builtin_amdgcn_mfma_f32_16x16x32_f16(a, wf[q][i], acc[i], 0,0,0);
    }
    // LN partial stats (rows=chains c=(lane>>4)*4+r, partial over our 64 j's per wave)
    float zz[4][4];
    float ps[4] = {0,0,0,0}, pq[4] = {0,0,0,0};
    #pragma unroll
    for (int i = 0; i < 4; ++i)
      #pragma unroll
      for (int r = 0; r < 4; ++r) {
        float v = acc[i][r] + bh[i];
        zz[i][r] = v; ps[r] += v; pq[r] += v*v;
      }
    #pragma unroll
    for (int m = 1; m < 16; m <<= 1)
      #pragma unroll
      for (int r = 0; r < 4; ++r) { ps[r] += __shfl_xor(ps[r], m); pq[r] += __shfl_xor(pq[r], m); }
    if ((lane & 15) == 0) {
      int g = lane >> 4;
      #pragma unroll
      for (int r = 0; r < 4; ++r) { stats[w][g*4+r][0] = ps[r]; stats[w][g*4+r][1] = pq[r]; }
    }
    __syncthreads();
    if (tid < 32) {
      int c = tid >> 1, sel = tid & 1;
      float v = stats[0][c][sel] + stats[1][c][sel] + stats[2][c][sel] + stats[3][c][sel];
      bstats[c][sel] = v;
      sex[(pbid ^ 8)*32 + c*2 + sel] = v;   // == bid*32 + ...
    }
    __syncthreads();   // barrier drains the sex stores before flag
    if (tid == 0)
      __hip_atomic_store(&Sflag[bid], (unsigned)(t+1), __ATOMIC_RELEASE, __HIP_MEMORY_SCOPE_AGENT);
    // write LNi prefetch to its LDS buffer (overlaps partner-stats wait)
    if (pf) {
      int c = tid >> 4, seg = tid & 15;
      *(uint4*)&lniS[(t+1)&1][c*264 + seg*16]     = p0;
      *(uint4*)&lniS[(t+1)&1][c*264 + seg*16 + 8] = p1;
    }
    if (tid == 0) {
      int guard = 0;
      while (__hip_atomic_load(&Sflag[pbid], __ATOMIC_ACQUIRE, __HIP_MEMORY_SCOPE_AGENT)
             < (unsigned)(t+1)) { __builtin_amdgcn_s_sleep(1); if (++guard > (1<<26)) break; }
    }
    __syncthreads();
    // finish LN + tanh + write h
    int g = lane >> 4;
    #pragma unroll
    for (int r = 0; r < 4; ++r) {
      int c = g*4 + r;
      float s  = bstats[c][0] + __hip_atomic_load(&sex[pbid*32 + c*2 + 0],
                                                  __ATOMIC_RELAXED, __HIP_MEMORY_SCOPE_AGENT);
      float qq = bstats[c][1] + __hip_atomic_load(&sex[pbid*32 + c*2 + 1],
                                                  __ATOMIC_RELAXED, __HIP_MEMORY_SCOPE_AGENT);
      float mu = s * (1.f/512.f);
      float rs = rsqrtf(qq*(1.f/512.f) - mu*mu + EPSF);
      #pragma unroll
      for (int i = 0; i < 4; ++i) {
        int jloc = (w*4+i)*16 + (lane & 15);
        int j = jh*256 + jloc;
        float pre = (zz[i][r] - mu)*rs*gh[i] + beh[i] + (float)lniS[t&1][c*264 + jloc];
        float e = __expf(2.f*pre);
        float hv = 1.f - 2.f*__builtin_amdgcn_rcpf(e + 1.f);
        int kth = j >> 5, laneh = c + 16*((j>>3)&3), ee = j & 7;
        hblob[(kth*64 + laneh)*8 + ee] = (_Float16)hv;
        if (l == 3) h3[((size_t)(ch*16+c)*2048 + t)*512 + j] = (_Float16)hv;
        if (t == TT-1) hfin[((size_t)l*32 + ch*16 + c)*512 + j] = hv;
      }
    }
    __syncthreads();
    // publish own h-half
    { const char* srcl = (const char*)&hblob[ownkt0*64*8] + tid*32;
      uint4 a = *(const uint4*)srcl, b2 = *(const uint4*)(srcl+16);
      char* dstg = (char*)hex + (size_t)bid*8192 + tid*32;
      *(uint4*)dstg = a; *(uint4*)(dstg+16) = b2; }
    __syncthreads();   // drain before flag
    if (tid == 0)
      __hip_atomic_store(&Hflag[bid], (unsigned)(t+1), __ATOMIC_RELEASE, __HIP_MEMORY_SCOPE_AGENT);
  }
}

// ---------------- phase C: out = h3*W_ho^T + b_ho + x ----------------
__launch_bounds__(256,1)
__global__ void k_gemm_out(const _Float16* __restrict__ h3,
                           const _Float16* __restrict__ wblob,
                           const float* __restrict__ b_ho,
                           const float* __restrict__ x,
                           float* __restrict__ out) {
  __shared__ __align__(16) _Float16 Bst[16384];
  __shared__ __align__(16) char     Ast[64*80];
  int tid = threadIdx.x, lane = tid & 63, w = tid >> 6;
  int rb0 = blockIdx.x * 64;
  float breg[8];
  #pragma unroll
  for (int i = 0; i < 8; ++i) breg[i] = b_ho[(w*8+i)*16 + (lane & 15)];
  f4 acc[4][8];
  #pragma unroll
  for (int mt = 0; mt < 4; ++mt)
    #pragma unroll
    for (int i = 0; i < 8; ++i) acc[mt][i] = (f4){0.f,0.f,0.f,0.f};
  for (int kt = 0; kt < 16; ++kt) {
    const _Float16* bsrc = wblob + (size_t)(128 + kt)*16384;  // wi=8 (W_ho)
    #pragma unroll
    for (int it = 0; it < 8; ++it) {
      int off = it*2048 + tid*8;
      *(uint4*)&Bst[off] = *(const uint4*)&bsrc[off];
    }
    { int row = tid >> 2, slot = tid & 3;
      const _Float16* asrc = h3 + (size_t)(rb0+row)*512 + kt*32 + slot*8;
      *(uint4*)&Ast[row*80 + slot*16] = *(const uint4*)asrc; }
    __syncthreads();
    h8 af[4];
    #pragma unroll
    for (int mt = 0; mt < 4; ++mt)
      af[mt] = *(const h8*)&Ast[(mt*16 + (lane&15))*80 + (lane>>4)*16];
    #pragma unroll
    for (int i = 0; i < 8; ++i) {
      h8 bf = *(const h8*)&Bst[((w*8+i)*64 + lane)*8];
      #pragma unroll
      for (int mt = 0; mt < 4; ++mt)
        acc[mt][i] = __builtin_amdgcn_mfma_f32_16x16x32_f16(af[mt], bf, acc[mt][i], 0,0,0);
    }
    __syncthreads();
  }
  #pragma unroll
  for (int mt = 0; mt < 4; ++mt)
    #pragma unroll
    for (int r = 0; r < 4; ++r) {
      int rglob = rb0 + mt*16 + (lane>>4)*4 + r;
      #pragma unroll
      for (int i = 0; i < 8; ++i) {
        int j = (w*8+i)*16 + (lane & 15);
        out[(size_t)rglob*512 + j] = acc[mt][i][r] + breg[i] + x[(size_t)rglob*512 + j];
      }
    }
}

extern "C" void kernel_launch(void* const* d_in, const int* in_sizes, int n_in,
                              void* d_out, int out_size, void* d_ws, size_t ws_size,
                              hipStream_t stream) {
  const float* x    = (const float*)d_in[0];
  const float* Wih  = (const float*)d_in[1];
  const float* bih  = (const float*)d_in[2];
  const float* gih  = (const float*)d_in[3];
  const float* beih = (const float*)d_in[4];
  const float* Whh  = (const float*)d_in[5];
  const float* bhh  = (const float*)d_in[6];
  const float* ghh  = (const float*)d_in[7];
  const float* behh = (const float*)d_in[8];
  const float* Who  = (const float*)d_in[9];
  const float* bho  = (const float*)d_in[10];
  if (ws_size < WS_END) return;   // need ~390 MiB scratch
  char* ws = (char*)d_ws;
  _Float16* x16   = (_Float16*)(ws + WS_X16);
  _Float16* wblob = (_Float16*)(ws + WS_WBLOB);
  _Float16* lni   = (_Float16*)(ws + WS_LNI);
  _Float16* h3    = (_Float16*)(ws + WS_H3);
  _Float16* hex   = (_Float16*)(ws + WS_HEX);
  float*    sex   = (float*)   (ws + WS_SEX);
  unsigned int* flags = (unsigned int*)(ws + WS_FLAGS);
  float* outp = (float*)d_out;

  hipMemsetAsync(flags, 0, 256, stream);
  k_prep_x  <<<16384, 256, 0, stream>>>(x, x16);
  k_prep_w  <<<144,   256, 0, stream>>>(Wih, Whh, Who, wblob);
  k_gemm_lni<<<4096,  256, 0, stream>>>(x16, wblob, bih, gih, beih, lni);
  k_rnn     <<<16,    256, 0, stream>>>(wblob, lni, bhh, ghh, behh, h3,
                                        outp + (size_t)BT*DD, hex, sex, flags);
  k_gemm_out<<<1024,  256, 0, stream>>>(h3, wblob, bho, x, outp);
}